// Round 12
// baseline (97.190 us; speedup 1.0000x reference)
//
#include <hip/hip_runtime.h>

// ConvCapsuleLayer: B=2, 48x48, IN_CAPS=8, ATOMS=16, KER=3, OUT_CAPS=16, R=3.
// Round-12: TWO pixels per 256-thread block (grid 2116). Each phase body is
// duplicated per-pixel as independent instruction streams sharing barriers:
// barriers/pixel halve and the latency-heavy fused phase gets 2 independent
// chains per thread. W fragments shared across pixels. LDS 52.5 KB ->
// 3 blocks/CU (launch_bounds(256,3), VGPR cap ~168 -> no spill risk).

#define IN_CAPS 8
#define OUT_CAPS 16
#define KK 9
#define KKIN 72
#define BATCH 2
#define H_IN 48
#define W_IN 48
#define HO 46
#define WO 46
#define CIN 136
#define NPIX (BATCH*HO*WO)   // 4232

typedef float v2f __attribute__((ext_vector_type(2)));
typedef float v4f __attribute__((ext_vector_type(4)));

__device__ __forceinline__ v2f lo2(v4f v) { return __builtin_shufflevector(v, v, 0, 1); }
__device__ __forceinline__ v2f hi2(v4f v) { return __builtin_shufflevector(v, v, 2, 3); }
__device__ __forceinline__ v2f fma2(v2f a, v2f b, v2f c) {
    return __builtin_elementwise_fma(a, b, c);
}

template<int CTRL>
__device__ __forceinline__ float dpp_f(float x) {
    return __int_as_float(
        __builtin_amdgcn_update_dpp(0, __float_as_int(x), CTRL, 0xF, 0xF, true));
}
__device__ __forceinline__ float row_sum16(float x) {
    x += dpp_f<0xB1>(x);    // quad_perm xor1
    x += dpp_f<0x4E>(x);    // quad_perm xor2
    x += dpp_f<0x124>(x);   // row_ror:4
    x += dpp_f<0x128>(x);   // row_ror:8
    return x;
}

__device__ __forceinline__ int pose_row(int k) {
    return k * 20 + ((k >> 3) & 1) * 4;   // skew {0,4}, no overlap (pad 4)
}
__device__ __forceinline__ int g_row(int o, int ic) {
    return (o * 8 + ic) * 20 + o * 4;
}

#define PSZ  1440   // pose_s floats per pixel
#define PTSZ 1216   // pose_t floats per pixel (16*76)
#define GSZ  2620   // g_s floats per pixel
#define CSZ  1216   // coup floats per pixel (16*76)

__global__ __launch_bounds__(256, 3)
void capsule_routing_kernel(const float* __restrict__ x,
                            const float* __restrict__ Wg,
                            float* __restrict__ out)
{
    __shared__ alignas(16) float pose_s[2 * PSZ];    // 11520 B
    __shared__ alignas(16) float pose_t[2 * PTSZ];   //  9728 B
    __shared__ float act_s[2 * KKIN];                //   576 B
    __shared__ alignas(16) float g_s[2 * GSZ];       // 20960 B
    __shared__ alignas(16) float coup_s[2 * CSZ];    //  9728 B
    // total 52512 B -> 3 blocks/CU

    const int tid = threadIdx.x;
    const int o = tid >> 4;
    const int e = tid & 15;
    const int c = e & 3;

    // ---- W row fragment from global (shared by both pixels):
    //      w01[ic]=(W[ic][o][c][0..1]), w23=(..[2..3]) ----
    v2f w01[IN_CAPS], w23[IN_CAPS];
    #pragma unroll
    for (int i = 0; i < IN_CAPS; ++i) {
        const v4f wv = *reinterpret_cast<const v4f*>(
            &Wg[((i * OUT_CAPS + o) * 4 + c) * 4]);
        w01[i] = lo2(wv);
        w23[i] = hi2(wv);
    }

    // ---- stage both pixels' patches ----
    #pragma unroll
    for (int pix = 0; pix < 2; ++pix) {
        const int n   = blockIdx.x * 2 + pix;
        const int b   = n / (HO * WO);
        const int rem = n - b * (HO * WO);
        const int ho  = rem / WO;
        const int wo  = rem - ho * WO;
        float* ps = &pose_s[pix * PSZ];
        float* pt = &pose_t[pix * PTSZ];
        float* as = &act_s[pix * KKIN];
        for (int idx = tid; idx < KK * CIN; idx += 256) {
            int p  = idx / CIN;
            int cc = idx - p * CIN;
            int py = p / 3, px = p - py * 3;
            float val = x[(((b * H_IN + ho + py) * W_IN) + (wo + px)) * CIN + cc];
            int ic = cc / 17;
            int aa = cc - ic * 17;
            int k  = p * IN_CAPS + ic;
            if (aa == 16) as[k] = val;
            else { ps[pose_row(k) + aa] = val; pt[aa * 76 + k] = val; }
        }
    }
    __syncthreads();

    // ---- r=0 coupling: softmax(0)*act = act/16 (both pixels) ----
    if (tid < KKIN) {
        #pragma unroll
        for (int pix = 0; pix < 2; ++pix) {
            float cv = act_s[pix * KKIN + tid] * 0.0625f;
            #pragma unroll
            for (int j = 0; j < OUT_CAPS; ++j)
                coup_s[pix * CSZ + j * 76 + tid] = cv;
        }
    }
    __syncthreads();

    // fused-phase ownership: (kf = tid>>1, hf = tid&1), 8 o's per pixel
    const int kf  = tid >> 1;
    const int hf  = tid & 1;
    const int ick = kf & 7;
    float lreg8[2][8] = {{0.f,0.f,0.f,0.f,0.f,0.f,0.f,0.f},
                         {0.f,0.f,0.f,0.f,0.f,0.f,0.f,0.f}};

    float v[2] = {0.f, 0.f};
    #pragma unroll 1
    for (int r = 0; r < 3; ++r) {
        // ---- phase B + C per pixel (independent chains) ----
        #pragma unroll
        for (int pix = 0; pix < 2; ++pix) {
            const v4f* cp = reinterpret_cast<const v4f*>(&coup_s[pix * CSZ + o * 76]);
            const v4f* pp = reinterpret_cast<const v4f*>(&pose_t[pix * PTSZ + e * 76]);
            v2f M01 = {0.f,0.f}, M23 = {0.f,0.f}, M45 = {0.f,0.f}, M67 = {0.f,0.f};
            #pragma unroll
            for (int p = 0; p < KK; ++p) {
                const v4f c0 = cp[2*p], c1 = cp[2*p+1];
                const v4f q0 = pp[2*p], q1 = pp[2*p+1];
                M01 = fma2(lo2(c0), lo2(q0), M01);
                M23 = fma2(hi2(c0), hi2(q0), M23);
                M45 = fma2(lo2(c1), lo2(q1), M45);
                M67 = fma2(hi2(c1), hi2(q1), M67);
            }
            const float Mc[8] = {M01.x, M01.y, M23.x, M23.y,
                                 M45.x, M45.y, M67.x, M67.y};
            v2f U01 = {0.f,0.f}, U23 = {0.f,0.f};
            #pragma unroll
            for (int ic = 0; ic < 8; ++ic) {
                const v2f mm = {Mc[ic], Mc[ic]};
                U01 = fma2(w01[ic], mm, U01);
                U23 = fma2(w23[ic], mm, U23);
            }
            float Z0 = U01.x, Z1 = U01.y, Z2 = U23.x, Z3 = U23.y;
            Z0 += dpp_f<0xB1>(Z0); Z1 += dpp_f<0xB1>(Z1);
            Z2 += dpp_f<0xB1>(Z2); Z3 += dpp_f<0xB1>(Z3);
            Z0 += dpp_f<0x4E>(Z0); Z1 += dpp_f<0x4E>(Z1);
            Z2 += dpp_f<0x4E>(Z2); Z3 += dpp_f<0x4E>(Z3);
            const float s = (c == 0) ? Z0 : (c == 1) ? Z1 : (c == 2) ? Z2 : Z3;
            const float sq = row_sum16(s * s);
            v[pix] = s * (sq / ((1.f + sq) * sqrtf(sq + 1e-7f)));
        }

        if (r < 2) {
            // ---- G build per pixel ----
            #pragma unroll
            for (int pix = 0; pix < 2; ++pix) {
                const float vq0 = dpp_f<0x00>(v[pix]);
                const float vq1 = dpp_f<0x55>(v[pix]);
                const float vq2 = dpp_f<0xAA>(v[pix]);
                const float vq3 = dpp_f<0xFF>(v[pix]);
                const v2f vq01 = {vq0, vq1};
                const v2f vq23 = {vq2, vq3};
                #pragma unroll
                for (int ic = 0; ic < 8; ++ic) {
                    v2f h = fma2(w23[ic], vq23, w01[ic] * vq01);
                    g_s[pix * GSZ + g_row(o, ic) + e] = h.x + h.y;
                }
            }
            __syncthreads();
            // ---- FUSED phase D part2 + phase A, both pixels per thread ----
            if (tid < 2 * KKIN) {
                #pragma unroll
                for (int pix = 0; pix < 2; ++pix) {
                    const v4f* pk = reinterpret_cast<const v4f*>(
                        &pose_s[pix * PSZ + pose_row(kf)]);
                    const v4f p0 = pk[0], p1 = pk[1], p2 = pk[2], p3 = pk[3];
                    const v2f q0 = lo2(p0), q1 = hi2(p0), q2 = lo2(p1), q3 = hi2(p1);
                    const v2f q4 = lo2(p2), q5 = hi2(p2), q6 = lo2(p3), q7 = hi2(p3);
                    float lg[8];
                    #pragma unroll
                    for (int j = 0; j < 8; ++j) {
                        const int oo = hf * 8 + j;
                        const v4f* gp = reinterpret_cast<const v4f*>(
                            &g_s[pix * GSZ + g_row(oo, ick)]);
                        const v4f g0 = gp[0], g1 = gp[1], g2 = gp[2], g3 = gp[3];
                        v2f A  = fma2(q2, lo2(g1), fma2(q4, lo2(g2),
                                  fma2(q6, lo2(g3), q0 * lo2(g0))));
                        v2f Bv = fma2(q3, hi2(g1), fma2(q5, hi2(g2),
                                  fma2(q7, hi2(g3), q1 * hi2(g0))));
                        lreg8[pix][j] += (A.x + A.y) + (Bv.x + Bv.y);
                        lg[j] = lreg8[pix][j];
                    }
                    float mx = -1e30f;
                    #pragma unroll
                    for (int j = 0; j < 8; ++j) mx = fmaxf(mx, lg[j]);
                    mx = fmaxf(mx, dpp_f<0xB1>(mx));
                    float sum = 0.f;
                    #pragma unroll
                    for (int j = 0; j < 8; ++j) { lg[j] = __expf(lg[j] - mx); sum += lg[j]; }
                    sum += dpp_f<0xB1>(sum);
                    const float scale = act_s[pix * KKIN + kf] / sum;
                    #pragma unroll
                    for (int j = 0; j < 8; ++j)
                        coup_s[pix * CSZ + (hf * 8 + j) * 76 + kf] = lg[j] * scale;
                }
            }
            __syncthreads();
        }
    }

    // ---- out[n][o][e], coalesced, both pixels ----
    out[(blockIdx.x * 2 + 0) * 256 + tid] = v[0];
    out[(blockIdx.x * 2 + 1) * 256 + tid] = v[1];
}

extern "C" void kernel_launch(void* const* d_in, const int* in_sizes, int n_in,
                              void* d_out, int out_size, void* d_ws, size_t ws_size,
                              hipStream_t stream) {
    const float* x  = (const float*)d_in[0];   // [2,48,48,136] fp32
    const float* Wt = (const float*)d_in[1];   // [8,16,4,4]    fp32
    float* outp = (float*)d_out;               // [2,46,46,16,16] fp32
    capsule_routing_kernel<<<dim3(NPIX / 2), dim3(256), 0, stream>>>(x, Wt, outp);
}